// Round 1
// baseline (1103.191 us; speedup 1.0000x reference)
//
#include <hip/hip_runtime.h>
#include <hip/hip_bf16.h>

#define TT 2048
#define BB 4
#define HH 8
#define KK 256
#define MM (BB*TT)      // 8192 tokens
#define NQKV 6144

typedef __attribute__((ext_vector_type(8))) short bf16x8;
typedef __attribute__((ext_vector_type(4))) float f32x4;

// ---------------- convert fp32 -> bf16 (vectorized) ----------------
__global__ __launch_bounds__(256) void cvt_k(const float* __restrict__ in,
                                             __hip_bfloat16* __restrict__ out, int n) {
    int i = (blockIdx.x * 256 + threadIdx.x) * 4;
    if (i + 3 < n) {
        float4 v = *(const float4*)(in + i);
        out[i + 0] = __float2bfloat16(v.x);
        out[i + 1] = __float2bfloat16(v.y);
        out[i + 2] = __float2bfloat16(v.z);
        out[i + 3] = __float2bfloat16(v.w);
    }
}

// ---------------- transpose + convert: in (R,C) f32 -> out (C,R) bf16 ----------------
__global__ __launch_bounds__(256) void transpose_cvt(const float* __restrict__ in,
                                                     __hip_bfloat16* __restrict__ out,
                                                     int R, int C) {
    __shared__ float tile[32][33];
    int c0 = blockIdx.x * 32, r0 = blockIdx.y * 32;
    int tx = threadIdx.x & 31, ty = threadIdx.x >> 5;   // ty 0..7
    #pragma unroll
    for (int i = ty; i < 32; i += 8)
        tile[i][tx] = in[(size_t)(r0 + i) * C + c0 + tx];
    __syncthreads();
    #pragma unroll
    for (int i = ty; i < 32; i += 8)
        out[(size_t)(c0 + i) * R + r0 + tx] = __float2bfloat16(tile[tx][i]);
}

// ---------------- transpose V slice of QKV into VT (B*H, 256, T) bf16 ----------------
__global__ __launch_bounds__(256) void transpose_v(const __hip_bfloat16* __restrict__ QKV,
                                                   __hip_bfloat16* __restrict__ VT) {
    __shared__ __hip_bfloat16 tile[32][33];
    int bh = blockIdx.z, b = bh >> 3, h = bh & 7;
    int t0 = blockIdx.x * 32, d0 = blockIdx.y * 32;
    int tx = threadIdx.x & 31, ty = threadIdx.x >> 5;
    const __hip_bfloat16* src = QKV + (size_t)b * TT * NQKV + 4096 + h * KK;
    #pragma unroll
    for (int i = ty; i < 32; i += 8)
        tile[i][tx] = src[(size_t)(t0 + i) * NQKV + d0 + tx];
    __syncthreads();
    __hip_bfloat16* dst = VT + (size_t)bh * KK * TT;
    #pragma unroll
    for (int i = ty; i < 32; i += 8)
        dst[(size_t)(d0 + i) * TT + t0 + tx] = tile[tx][i];
}

// ---------------- GEMM: C(M,N) = A(M,Kd) @ Bt(N,Kd)^T, bf16 in, f32 acc ----------------
// EPI 0: out bf16, *= scale for col<4096 (QKV q/k scaling)
// EPI 1: out f32 = acc + bias[col] + res[idx]
// EPI 2: out bf16 = relu(acc + bias[col])
template<int EPI>
__global__ __launch_bounds__(256) void gemm_k(const __hip_bfloat16* __restrict__ A,
                                              const __hip_bfloat16* __restrict__ Bt,
                                              int M, int N, int Kd,
                                              const float* __restrict__ bias,
                                              const float* __restrict__ res,
                                              void* __restrict__ outp, float scale) {
    constexpr int LDSW = 40;                 // 32 + 8 pad: 80B rows, 16B aligned, 2-way banks
    __shared__ short sA[2][128 * LDSW];
    __shared__ short sB[2][128 * LDSW];
    int tid = threadIdx.x, lane = tid & 63, wave = tid >> 6;
    int m0 = blockIdx.y * 128, n0 = blockIdx.x * 128;
    int wm = (wave >> 1) * 64, wn = (wave & 1) * 64;
    f32x4 acc[4][4] = {};
    const int NT = Kd >> 5;

    int c0 = tid, c1 = tid + 256;
    int ar0 = c0 >> 2, as0 = (c0 & 3) * 8;
    int ar1 = c1 >> 2, as1 = (c1 & 3) * 8;

    uint4 ra0, ra1, rb0, rb1;
    auto LOAD = [&](int kt) {
        size_t ka = (size_t)kt * 32;
        ra0 = *(const uint4*)(A + (size_t)(m0 + ar0) * Kd + ka + as0);
        ra1 = *(const uint4*)(A + (size_t)(m0 + ar1) * Kd + ka + as1);
        rb0 = *(const uint4*)(Bt + (size_t)(n0 + ar0) * Kd + ka + as0);
        rb1 = *(const uint4*)(Bt + (size_t)(n0 + ar1) * Kd + ka + as1);
    };
    auto STORE = [&](int buf) {
        *(uint4*)&sA[buf][ar0 * LDSW + as0] = ra0;
        *(uint4*)&sA[buf][ar1 * LDSW + as1] = ra1;
        *(uint4*)&sB[buf][ar0 * LDSW + as0] = rb0;
        *(uint4*)&sB[buf][ar1 * LDSW + as1] = rb1;
    };

    LOAD(0); STORE(0); __syncthreads();
    int cur = 0;
    for (int kt = 0; kt < NT; ++kt) {
        if (kt + 1 < NT) LOAD(kt + 1);
        bf16x8 af[4], bfr[4];
        #pragma unroll
        for (int mf = 0; mf < 4; ++mf)
            af[mf] = *(const bf16x8*)&sA[cur][(wm + mf * 16 + (lane & 15)) * LDSW + (lane >> 4) * 8];
        #pragma unroll
        for (int nf = 0; nf < 4; ++nf)
            bfr[nf] = *(const bf16x8*)&sB[cur][(wn + nf * 16 + (lane & 15)) * LDSW + (lane >> 4) * 8];
        #pragma unroll
        for (int mf = 0; mf < 4; ++mf)
            #pragma unroll
            for (int nf = 0; nf < 4; ++nf)
                acc[mf][nf] = __builtin_amdgcn_mfma_f32_16x16x32_bf16(af[mf], bfr[nf], acc[mf][nf], 0, 0, 0);
        if (kt + 1 < NT) STORE(cur ^ 1);
        __syncthreads();
        cur ^= 1;
    }

    #pragma unroll
    for (int mf = 0; mf < 4; ++mf) {
        int rowb = m0 + wm + mf * 16 + ((lane >> 4) * 4);
        #pragma unroll
        for (int nf = 0; nf < 4; ++nf) {
            int col = n0 + wn + nf * 16 + (lane & 15);
            #pragma unroll
            for (int r = 0; r < 4; ++r) {
                float v = acc[mf][nf][r];
                size_t idx = (size_t)(rowb + r) * N + col;
                if (EPI == 0) {
                    v *= (col < 4096) ? scale : 1.0f;
                    ((__hip_bfloat16*)outp)[idx] = __float2bfloat16(v);
                } else if (EPI == 1) {
                    v += bias[col] + res[idx];
                    ((float*)outp)[idx] = v;
                } else {
                    v += bias[col];
                    v = v > 0.0f ? v : 0.0f;
                    ((__hip_bfloat16*)outp)[idx] = __float2bfloat16(v);
                }
            }
        }
    }
}

// ---------------- flash attention (causal), 64 q-rows/block, 4 waves ----------------
__global__ __launch_bounds__(256) void attn_k(const __hip_bfloat16* __restrict__ QKV,
                                              const __hip_bfloat16* __restrict__ VT,
                                              __hip_bfloat16* __restrict__ O) {
    __shared__ __hip_bfloat16 Pl[4][16 * 72];   // per-wave P tile, stride 72 (2-way banks)
    int lane = threadIdx.x & 63, wave = threadIdx.x >> 6;
    int bh = blockIdx.y, b = bh >> 3, h = bh & 7;
    int q0 = blockIdx.x * 64;
    const __hip_bfloat16* Qb = QKV + (size_t)b * TT * NQKV + h * KK;
    const __hip_bfloat16* Kb = Qb + 2048;
    const __hip_bfloat16* Vtb = VT + (size_t)bh * KK * TT;

    int l15 = lane & 15, koff = (lane >> 4) * 8;
    int qrow = q0 + wave * 16 + l15;
    bf16x8 qf[8];
    #pragma unroll
    for (int kk = 0; kk < 8; ++kk)
        qf[kk] = *(const bf16x8*)(Qb + (size_t)qrow * NQKV + kk * 32 + koff);

    f32x4 Oa[16] = {};
    float mrow[4] = {-__builtin_inff(), -__builtin_inff(), -__builtin_inff(), -__builtin_inff()};
    float lrow[4] = {0.f, 0.f, 0.f, 0.f};

    for (int s0 = 0; s0 <= q0; s0 += 64) {
        f32x4 S[4] = {};
        #pragma unroll
        for (int nf = 0; nf < 4; ++nf) {
            const __hip_bfloat16* kp = Kb + (size_t)(s0 + nf * 16 + l15) * NQKV + koff;
            #pragma unroll
            for (int kk = 0; kk < 8; ++kk) {
                bf16x8 kf = *(const bf16x8*)(kp + kk * 32);
                S[nf] = __builtin_amdgcn_mfma_f32_16x16x32_bf16(qf[kk], kf, S[nf], 0, 0, 0);
            }
        }
        if (s0 == q0) {   // diagonal tile: causal mask
            #pragma unroll
            for (int nf = 0; nf < 4; ++nf) {
                int col = s0 + nf * 16 + l15;
                #pragma unroll
                for (int r = 0; r < 4; ++r) {
                    int row = q0 + wave * 16 + (lane >> 4) * 4 + r;
                    if (col > row) S[nf][r] = -__builtin_inff();
                }
            }
        }
        #pragma unroll
        for (int r = 0; r < 4; ++r) {
            float mx = fmaxf(fmaxf(S[0][r], S[1][r]), fmaxf(S[2][r], S[3][r]));
            #pragma unroll
            for (int d = 1; d < 16; d <<= 1) mx = fmaxf(mx, __shfl_xor(mx, d));
            float mn = fmaxf(mrow[r], mx);
            float alpha = __expf(mrow[r] - mn);   // -inf first tile -> 0
            mrow[r] = mn;
            float ps = 0.f;
            #pragma unroll
            for (int nf = 0; nf < 4; ++nf) {
                float p = __expf(S[nf][r] - mn);
                S[nf][r] = p; ps += p;
            }
            #pragma unroll
            for (int d = 1; d < 16; d <<= 1) ps += __shfl_xor(ps, d);
            lrow[r] = lrow[r] * alpha + ps;
            #pragma unroll
            for (int nf2 = 0; nf2 < 16; ++nf2) Oa[nf2][r] *= alpha;
        }
        // P (f32 regs, C-layout) -> bf16 LDS row-major [16][72]
        #pragma unroll
        for (int nf = 0; nf < 4; ++nf)
            #pragma unroll
            for (int r = 0; r < 4; ++r)
                Pl[wave][((lane >> 4) * 4 + r) * 72 + nf * 16 + l15] = __float2bfloat16(S[nf][r]);
        __syncthreads();   // intra-wave LDS write->read ordering (cheap, safe)
        // PV: O += P @ V  (V^T rows contiguous)
        #pragma unroll
        for (int nf2 = 0; nf2 < 16; ++nf2) {
            const __hip_bfloat16* vp = Vtb + (size_t)(nf2 * 16 + l15) * TT + s0 + koff;
            #pragma unroll
            for (int kk2 = 0; kk2 < 2; ++kk2) {
                bf16x8 pa = *(const bf16x8*)&Pl[wave][l15 * 72 + kk2 * 32 + koff];
                bf16x8 vb = *(const bf16x8*)(vp + kk2 * 32);
                Oa[nf2] = __builtin_amdgcn_mfma_f32_16x16x32_bf16(pa, vb, Oa[nf2], 0, 0, 0);
            }
        }
        __syncthreads();
    }
    #pragma unroll
    for (int nf2 = 0; nf2 < 16; ++nf2) {
        int col = nf2 * 16 + l15;
        #pragma unroll
        for (int r = 0; r < 4; ++r) {
            int t = q0 + wave * 16 + (lane >> 4) * 4 + r;
            O[((size_t)b * TT + t) * 2048 + h * KK + col] = __float2bfloat16(Oa[nf2][r] / lrow[r]);
        }
    }
}

// ---------------- row LayerNorm over K=256, 4 rows/block ----------------
__global__ __launch_bounds__(256) void layernorm_k(const float* __restrict__ y,
                                                   const float* __restrict__ g,
                                                   const float* __restrict__ be,
                                                   float* __restrict__ out_f,
                                                   __hip_bfloat16* __restrict__ out_b) {
    int row = blockIdx.x * 4 + (threadIdx.x >> 6);
    int lane = threadIdx.x & 63;
    float4 v = *(const float4*)(y + (size_t)row * 256 + lane * 4);
    float s = v.x + v.y + v.z + v.w;
    #pragma unroll
    for (int d = 1; d < 64; d <<= 1) s += __shfl_xor(s, d);
    float mu = s * (1.0f / 256.0f);
    float dx = v.x - mu, dy = v.y - mu, dz = v.z - mu, dw = v.w - mu;
    float q = dx * dx + dy * dy + dz * dz + dw * dw;
    #pragma unroll
    for (int d = 1; d < 64; d <<= 1) q += __shfl_xor(q, d);
    float rs = rsqrtf(q * (1.0f / 256.0f) + 1e-5f);
    float4 gg = *(const float4*)(g + lane * 4);
    float4 bb = *(const float4*)(be + lane * 4);
    float4 o;
    o.x = dx * rs * gg.x + bb.x;
    o.y = dy * rs * gg.y + bb.y;
    o.z = dz * rs * gg.z + bb.z;
    o.w = dw * rs * gg.w + bb.w;
    *(float4*)(out_f + (size_t)row * 256 + lane * 4) = o;
    if (out_b) {
        size_t i = (size_t)row * 256 + lane * 4;
        out_b[i + 0] = __float2bfloat16(o.x);
        out_b[i + 1] = __float2bfloat16(o.y);
        out_b[i + 2] = __float2bfloat16(o.z);
        out_b[i + 3] = __float2bfloat16(o.w);
    }
}

extern "C" void kernel_launch(void* const* d_in, const int* in_sizes, int n_in,
                              void* d_out, int out_size, void* d_ws, size_t ws_size,
                              hipStream_t stream) {
    const float* x  = (const float*)d_in[0];
    const float* wq = (const float*)d_in[1];
    const float* wk = (const float*)d_in[2];
    const float* wv = (const float*)d_in[3];
    const float* wu = (const float*)d_in[4];
    const float* bu = (const float*)d_in[5];
    const float* w1 = (const float*)d_in[6];
    const float* b1 = (const float*)d_in[7];
    const float* w2 = (const float*)d_in[8];
    const float* b2 = (const float*)d_in[9];
    const float* g1 = (const float*)d_in[10];
    const float* be1 = (const float*)d_in[11];
    const float* g2 = (const float*)d_in[12];
    const float* be2 = (const float*)d_in[13];

    char* p = (char*)d_ws;
    auto alloc = [&](size_t bytes) { char* r = p; p += bytes; return r; };
    __hip_bfloat16* xb    = (__hip_bfloat16*)alloc((size_t)MM * KK * 2);
    __hip_bfloat16* wqkvT = (__hip_bfloat16*)alloc((size_t)NQKV * KK * 2);
    __hip_bfloat16* wuT   = (__hip_bfloat16*)alloc((size_t)KK * 2048 * 2);
    __hip_bfloat16* w1T   = (__hip_bfloat16*)alloc((size_t)1024 * KK * 2);
    __hip_bfloat16* w2T   = (__hip_bfloat16*)alloc((size_t)KK * 1024 * 2);
    __hip_bfloat16* qkv   = (__hip_bfloat16*)alloc((size_t)MM * NQKV * 2);
    __hip_bfloat16* vt    = (__hip_bfloat16*)alloc((size_t)32 * KK * TT * 2);
    __hip_bfloat16* attn  = (__hip_bfloat16*)alloc((size_t)MM * 2048 * 2);
    float*          y1    = (float*)alloc((size_t)MM * KK * 4);
    float*          x1    = (float*)alloc((size_t)MM * KK * 4);
    __hip_bfloat16* x1b   = (__hip_bfloat16*)alloc((size_t)MM * KK * 2);
    __hip_bfloat16* hid   = (__hip_bfloat16*)alloc((size_t)MM * 1024 * 2);
    float*          y2    = (float*)alloc((size_t)MM * KK * 4);

    // 1. convert x, transpose-convert weights
    cvt_k<<<(MM * KK) / 1024, 256, 0, stream>>>(x, xb, MM * KK);
    transpose_cvt<<<dim3(64, 8),  256, 0, stream>>>(wq, wqkvT,             256, 2048);
    transpose_cvt<<<dim3(64, 8),  256, 0, stream>>>(wk, wqkvT + 2048 * 256, 256, 2048);
    transpose_cvt<<<dim3(64, 8),  256, 0, stream>>>(wv, wqkvT + 4096 * 256, 256, 2048);
    transpose_cvt<<<dim3(8, 64),  256, 0, stream>>>(wu, wuT, 2048, 256);
    transpose_cvt<<<dim3(32, 8),  256, 0, stream>>>(w1, w1T, 256, 1024);
    transpose_cvt<<<dim3(8, 32),  256, 0, stream>>>(w2, w2T, 1024, 256);

    // 2. QKV projection (q,k scaled by 256^-0.25 = 0.25)
    gemm_k<0><<<dim3(NQKV / 128, MM / 128), 256, 0, stream>>>(
        xb, wqkvT, MM, NQKV, 256, nullptr, nullptr, qkv, 0.25f);

    // 3. V transpose + flash attention
    transpose_v<<<dim3(64, 8, 32), 256, 0, stream>>>(qkv, vt);
    attn_k<<<dim3(TT / 64, BB * HH), 256, 0, stream>>>(qkv, vt, attn);

    // 4. output proj + residual, LN1
    gemm_k<1><<<dim3(2, MM / 128), 256, 0, stream>>>(
        attn, wuT, MM, 256, 2048, bu, x, y1, 1.0f);
    layernorm_k<<<MM / 4, 256, 0, stream>>>(y1, g1, be1, x1, x1b);

    // 5. FFN
    gemm_k<2><<<dim3(8, MM / 128), 256, 0, stream>>>(
        x1b, w1T, MM, 1024, 256, b1, nullptr, hid, 1.0f);
    gemm_k<1><<<dim3(2, MM / 128), 256, 0, stream>>>(
        hid, w2T, MM, 256, 1024, b2, x1, y2, 1.0f);
    layernorm_k<<<MM / 4, 256, 0, stream>>>(y2, g2, be2, (float*)d_out, nullptr);
}

// Round 2
// 323.605 us; speedup vs baseline: 3.4091x; 3.4091x over previous
//
#include <hip/hip_runtime.h>
#include <hip/hip_bf16.h>

#define TT 2048
#define BB 4
#define HH 8
#define KK 256
#define MM (BB*TT)      // 8192 tokens
#define NQKV 6144

typedef __attribute__((ext_vector_type(8))) short bf16x8;
typedef __attribute__((ext_vector_type(4))) float f32x4;

__device__ __forceinline__ void gld_lds16(const void* g, void* lds) {
    __builtin_amdgcn_global_load_lds(
        (const __attribute__((address_space(1))) unsigned int*)g,
        (__attribute__((address_space(3))) unsigned int*)lds, 16, 0, 0);
}

// ---------------- convert fp32 -> bf16 (vectorized) ----------------
__global__ __launch_bounds__(256) void cvt_k(const float* __restrict__ in,
                                             __hip_bfloat16* __restrict__ out, int n) {
    int i = (blockIdx.x * 256 + threadIdx.x) * 4;
    if (i + 3 < n) {
        float4 v = *(const float4*)(in + i);
        out[i + 0] = __float2bfloat16(v.x);
        out[i + 1] = __float2bfloat16(v.y);
        out[i + 2] = __float2bfloat16(v.z);
        out[i + 3] = __float2bfloat16(v.w);
    }
}

// ---------------- transpose + convert: in (R,C) f32 -> out (C,R) bf16 ----------------
__global__ __launch_bounds__(256) void transpose_cvt(const float* __restrict__ in,
                                                     __hip_bfloat16* __restrict__ out,
                                                     int R, int C) {
    __shared__ float tile[32][33];
    int c0 = blockIdx.x * 32, r0 = blockIdx.y * 32;
    int tx = threadIdx.x & 31, ty = threadIdx.x >> 5;   // ty 0..7
    #pragma unroll
    for (int i = ty; i < 32; i += 8)
        tile[i][tx] = in[(size_t)(r0 + i) * C + c0 + tx];
    __syncthreads();
    #pragma unroll
    for (int i = ty; i < 32; i += 8)
        out[(size_t)(c0 + i) * R + r0 + tx] = __float2bfloat16(tile[tx][i]);
}

// ---------------- transpose V slice of QKV into VT (B*H, 256, T) bf16 ----------------
__global__ __launch_bounds__(256) void transpose_v(const __hip_bfloat16* __restrict__ QKV,
                                                   __hip_bfloat16* __restrict__ VT) {
    __shared__ __hip_bfloat16 tile[32][33];
    int bh = blockIdx.z, b = bh >> 3, h = bh & 7;
    int t0 = blockIdx.x * 32, d0 = blockIdx.y * 32;
    int tx = threadIdx.x & 31, ty = threadIdx.x >> 5;
    const __hip_bfloat16* src = QKV + (size_t)b * TT * NQKV + 4096 + h * KK;
    #pragma unroll
    for (int i = ty; i < 32; i += 8)
        tile[i][tx] = src[(size_t)(t0 + i) * NQKV + d0 + tx];
    __syncthreads();
    __hip_bfloat16* dst = VT + (size_t)bh * KK * TT;
    #pragma unroll
    for (int i = ty; i < 32; i += 8)
        dst[(size_t)(d0 + i) * TT + t0 + tx] = tile[tx][i];
}

// ---------------- GEMM: C(M,N) = A(M,Kd) @ Bt(N,Kd)^T, bf16 in, f32 acc ----------------
template<int EPI>
__global__ __launch_bounds__(256) void gemm_k(const __hip_bfloat16* __restrict__ A,
                                              const __hip_bfloat16* __restrict__ Bt,
                                              int M, int N, int Kd,
                                              const float* __restrict__ bias,
                                              const float* __restrict__ res,
                                              void* __restrict__ outp, float scale) {
    constexpr int LDSW = 40;
    __shared__ short sA[2][128 * LDSW];
    __shared__ short sB[2][128 * LDSW];
    int tid = threadIdx.x, lane = tid & 63, wave = tid >> 6;
    int m0 = blockIdx.y * 128, n0 = blockIdx.x * 128;
    int wm = (wave >> 1) * 64, wn = (wave & 1) * 64;
    f32x4 acc[4][4] = {};
    const int NT = Kd >> 5;

    int c0 = tid, c1 = tid + 256;
    int ar0 = c0 >> 2, as0 = (c0 & 3) * 8;
    int ar1 = c1 >> 2, as1 = (c1 & 3) * 8;

    uint4 ra0, ra1, rb0, rb1;
    auto LOAD = [&](int kt) {
        size_t ka = (size_t)kt * 32;
        ra0 = *(const uint4*)(A + (size_t)(m0 + ar0) * Kd + ka + as0);
        ra1 = *(const uint4*)(A + (size_t)(m0 + ar1) * Kd + ka + as1);
        rb0 = *(const uint4*)(Bt + (size_t)(n0 + ar0) * Kd + ka + as0);
        rb1 = *(const uint4*)(Bt + (size_t)(n0 + ar1) * Kd + ka + as1);
    };
    auto STORE = [&](int buf) {
        *(uint4*)&sA[buf][ar0 * LDSW + as0] = ra0;
        *(uint4*)&sA[buf][ar1 * LDSW + as1] = ra1;
        *(uint4*)&sB[buf][ar0 * LDSW + as0] = rb0;
        *(uint4*)&sB[buf][ar1 * LDSW + as1] = rb1;
    };

    LOAD(0); STORE(0); __syncthreads();
    int cur = 0;
    for (int kt = 0; kt < NT; ++kt) {
        if (kt + 1 < NT) LOAD(kt + 1);
        bf16x8 af[4], bfr[4];
        #pragma unroll
        for (int mf = 0; mf < 4; ++mf)
            af[mf] = *(const bf16x8*)&sA[cur][(wm + mf * 16 + (lane & 15)) * LDSW + (lane >> 4) * 8];
        #pragma unroll
        for (int nf = 0; nf < 4; ++nf)
            bfr[nf] = *(const bf16x8*)&sB[cur][(wn + nf * 16 + (lane & 15)) * LDSW + (lane >> 4) * 8];
        #pragma unroll
        for (int mf = 0; mf < 4; ++mf)
            #pragma unroll
            for (int nf = 0; nf < 4; ++nf)
                acc[mf][nf] = __builtin_amdgcn_mfma_f32_16x16x32_bf16(af[mf], bfr[nf], acc[mf][nf], 0, 0, 0);
        if (kt + 1 < NT) STORE(cur ^ 1);
        __syncthreads();
        cur ^= 1;
    }

    #pragma unroll
    for (int mf = 0; mf < 4; ++mf) {
        int rowb = m0 + wm + mf * 16 + ((lane >> 4) * 4);
        #pragma unroll
        for (int nf = 0; nf < 4; ++nf) {
            int col = n0 + wn + nf * 16 + (lane & 15);
            #pragma unroll
            for (int r = 0; r < 4; ++r) {
                float v = acc[mf][nf][r];
                size_t idx = (size_t)(rowb + r) * N + col;
                if (EPI == 0) {
                    v *= (col < 4096) ? scale : 1.0f;
                    ((__hip_bfloat16*)outp)[idx] = __float2bfloat16(v);
                } else if (EPI == 1) {
                    v += bias[col] + res[idx];
                    ((float*)outp)[idx] = v;
                } else {
                    v += bias[col];
                    v = v > 0.0f ? v : 0.0f;
                    ((__hip_bfloat16*)outp)[idx] = __float2bfloat16(v);
                }
            }
        }
    }
}

// ---------------- flash attention (causal), paired q-tiles, LDS-staged K/V ----------------
// grid: (16, 32). Block handles q-tiles {j, 31-j}: uniform 33 s0-iterations.
// K tile [64][256] bf16 (32KB) + VT tile [256][64] bf16 (32KB) staged via
// global_load_lds, XOR-swizzled (byte ^= (row&7)<<4) for conflict-free ds_read_b128.
__global__ __launch_bounds__(256, 2) void attn_k(const __hip_bfloat16* __restrict__ QKV,
                                                 const __hip_bfloat16* __restrict__ VT,
                                                 __hip_bfloat16* __restrict__ O) {
    __shared__ char Kl[32768];
    __shared__ char Vl[32768];
    __shared__ __hip_bfloat16 Pl[4][16 * 72];
    int lane = threadIdx.x & 63, wave = threadIdx.x >> 6;
    int bh = blockIdx.y, b = bh >> 3, h = bh & 7;
    const __hip_bfloat16* Qb = QKV + (size_t)b * TT * NQKV + h * KK;
    const __hip_bfloat16* Kb = Qb + 2048;
    const __hip_bfloat16* Vtb = VT + (size_t)bh * KK * TT;

    int l15 = lane & 15, koff = (lane >> 4) * 8;       // elements
    int koffB = koff * 2;                               // bytes

    #pragma unroll 1
    for (int half = 0; half < 2; ++half) {
        int jt = (half == 0) ? (int)blockIdx.x : 31 - (int)blockIdx.x;
        int q0 = jt * 64;
        int qrow = q0 + wave * 16 + l15;
        bf16x8 qf[8];
        #pragma unroll
        for (int kk = 0; kk < 8; ++kk)
            qf[kk] = *(const bf16x8*)(Qb + (size_t)qrow * NQKV + kk * 32 + koff);

        f32x4 Oa[16] = {};
        float mrow[4] = {-__builtin_inff(), -__builtin_inff(), -__builtin_inff(), -__builtin_inff()};
        float lrow[4] = {0.f, 0.f, 0.f, 0.f};

        #pragma unroll 1
        for (int s0 = 0; s0 <= q0; s0 += 64) {
            __syncthreads();   // all waves done reading previous tiles
            // ---- stage K tile: LDS byte L holds K[s0 + L/512][ ((L%512)^((row&7)<<4))/2 ]
            #pragma unroll
            for (int it = 0; it < 8; ++it) {
                int L = wave * 8192 + it * 1024 + lane * 16;
                int row = L >> 9;
                int cb = (L & 511) ^ ((row & 7) << 4);
                const char* src = (const char*)(Kb + (size_t)(s0 + row) * NQKV) + cb;
                gld_lds16(src, Kl + wave * 8192 + it * 1024);
            }
            // ---- stage VT tile: LDS byte L holds VT[L/128][s0 + ((L%128)^((row&7)<<4))/2]
            #pragma unroll
            for (int it = 0; it < 8; ++it) {
                int L = wave * 8192 + it * 1024 + lane * 16;
                int row = L >> 7;
                int cb = (L & 127) ^ ((row & 7) << 4);
                const char* src = (const char*)(Vtb + (size_t)row * TT + s0) + cb;
                gld_lds16(src, Vl + wave * 8192 + it * 1024);
            }
            asm volatile("s_waitcnt vmcnt(0)" ::: "memory");
            __syncthreads();   // tiles ready

            // ---- QK^T from LDS
            f32x4 S[4] = {};
            #pragma unroll
            for (int nf = 0; nf < 4; ++nf) {
                int r = nf * 16 + l15;
                int swz = (r & 7) << 4;
                #pragma unroll
                for (int kk = 0; kk < 8; ++kk) {
                    bf16x8 kf = *(const bf16x8*)(Kl + r * 512 + ((kk * 64 + koffB) ^ swz));
                    S[nf] = __builtin_amdgcn_mfma_f32_16x16x32_bf16(qf[kk], kf, S[nf], 0, 0, 0);
                }
            }
            if (s0 == q0) {   // diagonal tile: causal mask
                #pragma unroll
                for (int nf = 0; nf < 4; ++nf) {
                    int col = s0 + nf * 16 + l15;
                    #pragma unroll
                    for (int r = 0; r < 4; ++r) {
                        int row = q0 + wave * 16 + (lane >> 4) * 4 + r;
                        if (col > row) S[nf][r] = -__builtin_inff();
                    }
                }
            }
            // ---- online softmax (all 64 lanes active; reduce over 16 l15 lanes)
            #pragma unroll
            for (int r = 0; r < 4; ++r) {
                float mx = fmaxf(fmaxf(S[0][r], S[1][r]), fmaxf(S[2][r], S[3][r]));
                #pragma unroll
                for (int d = 1; d < 16; d <<= 1) mx = fmaxf(mx, __shfl_xor(mx, d));
                float mn = fmaxf(mrow[r], mx);
                float alpha = __expf(mrow[r] - mn);
                mrow[r] = mn;
                float ps = 0.f;
                #pragma unroll
                for (int nf = 0; nf < 4; ++nf) {
                    float p = __expf(S[nf][r] - mn);
                    S[nf][r] = p; ps += p;
                }
                #pragma unroll
                for (int d = 1; d < 16; d <<= 1) ps += __shfl_xor(ps, d);
                lrow[r] = lrow[r] * alpha + ps;
                #pragma unroll
                for (int nf2 = 0; nf2 < 16; ++nf2) Oa[nf2][r] *= alpha;
            }
            // ---- P -> per-wave LDS tile (in-wave ordering; no block barrier needed)
            #pragma unroll
            for (int nf = 0; nf < 4; ++nf)
                #pragma unroll
                for (int r = 0; r < 4; ++r)
                    Pl[wave][((lane >> 4) * 4 + r) * 72 + nf * 16 + l15] = __float2bfloat16(S[nf][r]);
            // ---- PV: O += P @ V  (VT tile in LDS, swizzled)
            bf16x8 pa[2];
            #pragma unroll
            for (int kk2 = 0; kk2 < 2; ++kk2)
                pa[kk2] = *(const bf16x8*)&Pl[wave][l15 * 72 + kk2 * 32 + koff];
            #pragma unroll
            for (int nf2 = 0; nf2 < 16; ++nf2) {
                int r = nf2 * 16 + l15;
                int swz = (r & 7) << 4;
                #pragma unroll
                for (int kk2 = 0; kk2 < 2; ++kk2) {
                    bf16x8 vb = *(const bf16x8*)(Vl + r * 128 + ((kk2 * 64 + koffB) ^ swz));
                    Oa[nf2] = __builtin_amdgcn_mfma_f32_16x16x32_bf16(pa[kk2], vb, Oa[nf2], 0, 0, 0);
                }
            }
        }
        // ---- write this q-tile's output
        float rcp[4];
        #pragma unroll
        for (int r = 0; r < 4; ++r) rcp[r] = 1.0f / lrow[r];
        #pragma unroll
        for (int nf2 = 0; nf2 < 16; ++nf2) {
            int col = nf2 * 16 + l15;
            #pragma unroll
            for (int r = 0; r < 4; ++r) {
                int t = q0 + wave * 16 + (lane >> 4) * 4 + r;
                O[((size_t)b * TT + t) * 2048 + h * KK + col] = __float2bfloat16(Oa[nf2][r] * rcp[r]);
            }
        }
    }
}

// ---------------- row LayerNorm over K=256, 4 rows/block ----------------
__global__ __launch_bounds__(256) void layernorm_k(const float* __restrict__ y,
                                                   const float* __restrict__ g,
                                                   const float* __restrict__ be,
                                                   float* __restrict__ out_f,
                                                   __hip_bfloat16* __restrict__ out_b) {
    int row = blockIdx.x * 4 + (threadIdx.x >> 6);
    int lane = threadIdx.x & 63;
    float4 v = *(const float4*)(y + (size_t)row * 256 + lane * 4);
    float s = v.x + v.y + v.z + v.w;
    #pragma unroll
    for (int d = 1; d < 64; d <<= 1) s += __shfl_xor(s, d);
    float mu = s * (1.0f / 256.0f);
    float dx = v.x - mu, dy = v.y - mu, dz = v.z - mu, dw = v.w - mu;
    float q = dx * dx + dy * dy + dz * dz + dw * dw;
    #pragma unroll
    for (int d = 1; d < 64; d <<= 1) q += __shfl_xor(q, d);
    float rs = rsqrtf(q * (1.0f / 256.0f) + 1e-5f);
    float4 gg = *(const float4*)(g + lane * 4);
    float4 bb = *(const float4*)(be + lane * 4);
    float4 o;
    o.x = dx * rs * gg.x + bb.x;
    o.y = dy * rs * gg.y + bb.y;
    o.z = dz * rs * gg.z + bb.z;
    o.w = dw * rs * gg.w + bb.w;
    *(float4*)(out_f + (size_t)row * 256 + lane * 4) = o;
    if (out_b) {
        size_t i = (size_t)row * 256 + lane * 4;
        out_b[i + 0] = __float2bfloat16(o.x);
        out_b[i + 1] = __float2bfloat16(o.y);
        out_b[i + 2] = __float2bfloat16(o.z);
        out_b[i + 3] = __float2bfloat16(o.w);
    }
}

extern "C" void kernel_launch(void* const* d_in, const int* in_sizes, int n_in,
                              void* d_out, int out_size, void* d_ws, size_t ws_size,
                              hipStream_t stream) {
    const float* x  = (const float*)d_in[0];
    const float* wq = (const float*)d_in[1];
    const float* wk = (const float*)d_in[2];
    const float* wv = (const float*)d_in[3];
    const float* wu = (const float*)d_in[4];
    const float* bu = (const float*)d_in[5];
    const float* w1 = (const float*)d_in[6];
    const float* b1 = (const float*)d_in[7];
    const float* w2 = (const float*)d_in[8];
    const float* b2 = (const float*)d_in[9];
    const float* g1 = (const float*)d_in[10];
    const float* be1 = (const float*)d_in[11];
    const float* g2 = (const float*)d_in[12];
    const float* be2 = (const float*)d_in[13];

    char* p = (char*)d_ws;
    auto alloc = [&](size_t bytes) { char* r = p; p += bytes; return r; };
    __hip_bfloat16* xb    = (__hip_bfloat16*)alloc((size_t)MM * KK * 2);
    __hip_bfloat16* wqkvT = (__hip_bfloat16*)alloc((size_t)NQKV * KK * 2);
    __hip_bfloat16* wuT   = (__hip_bfloat16*)alloc((size_t)KK * 2048 * 2);
    __hip_bfloat16* w1T   = (__hip_bfloat16*)alloc((size_t)1024 * KK * 2);
    __hip_bfloat16* w2T   = (__hip_bfloat16*)alloc((size_t)KK * 1024 * 2);
    __hip_bfloat16* qkv   = (__hip_bfloat16*)alloc((size_t)MM * NQKV * 2);
    __hip_bfloat16* vt    = (__hip_bfloat16*)alloc((size_t)32 * KK * TT * 2);
    __hip_bfloat16* attn  = (__hip_bfloat16*)alloc((size_t)MM * 2048 * 2);
    float*          y1    = (float*)alloc((size_t)MM * KK * 4);
    float*          x1    = (float*)alloc((size_t)MM * KK * 4);
    __hip_bfloat16* x1b   = (__hip_bfloat16*)alloc((size_t)MM * KK * 2);
    __hip_bfloat16* hid   = (__hip_bfloat16*)alloc((size_t)MM * 1024 * 2);
    float*          y2    = (float*)alloc((size_t)MM * KK * 4);

    cvt_k<<<(MM * KK) / 1024, 256, 0, stream>>>(x, xb, MM * KK);
    transpose_cvt<<<dim3(64, 8),  256, 0, stream>>>(wq, wqkvT,             256, 2048);
    transpose_cvt<<<dim3(64, 8),  256, 0, stream>>>(wk, wqkvT + 2048 * 256, 256, 2048);
    transpose_cvt<<<dim3(64, 8),  256, 0, stream>>>(wv, wqkvT + 4096 * 256, 256, 2048);
    transpose_cvt<<<dim3(8, 64),  256, 0, stream>>>(wu, wuT, 2048, 256);
    transpose_cvt<<<dim3(32, 8),  256, 0, stream>>>(w1, w1T, 256, 1024);
    transpose_cvt<<<dim3(8, 32),  256, 0, stream>>>(w2, w2T, 1024, 256);

    gemm_k<0><<<dim3(NQKV / 128, MM / 128), 256, 0, stream>>>(
        xb, wqkvT, MM, NQKV, 256, nullptr, nullptr, qkv, 0.25f);

    transpose_v<<<dim3(64, 8, 32), 256, 0, stream>>>(qkv, vt);
    attn_k<<<dim3(16, BB * HH), 256, 0, stream>>>(qkv, vt, attn);

    gemm_k<1><<<dim3(2, MM / 128), 256, 0, stream>>>(
        attn, wuT, MM, 256, 2048, bu, x, y1, 1.0f);
    layernorm_k<<<MM / 4, 256, 0, stream>>>(y1, g1, be1, x1, x1b);

    gemm_k<2><<<dim3(8, MM / 128), 256, 0, stream>>>(
        x1b, w1T, MM, 1024, 256, b1, nullptr, hid, 1.0f);
    gemm_k<1><<<dim3(2, MM / 128), 256, 0, stream>>>(
        hid, w2T, MM, 256, 1024, b2, x1, y2, 1.0f);
    layernorm_k<<<MM / 4, 256, 0, stream>>>(y2, g2, be2, (float*)d_out, nullptr);
}